// Round 8
// baseline (541.281 us; speedup 1.0000x reference)
//
#include <hip/hip_runtime.h>
#include <stdint.h>

// Problem constants (Attention_39556648796173)
#define TTOK  8192
#define DIMM  2048
#define NH    16
#define NKV   8
#define HD    128
#define SEQ   1024
#define BATCH 8
#define BLKSZ 16

typedef unsigned short u16;
typedef __attribute__((ext_vector_type(8))) short bfrag;   // 8 x bf16 (4 VGPRs)
typedef __attribute__((ext_vector_type(4))) float f32x4;   // MFMA accumulator

__device__ __forceinline__ float bf2f(u16 u) {
  unsigned int v = ((unsigned int)u) << 16;
  float f; __builtin_memcpy(&f, &v, 4); return f;
}
__device__ __forceinline__ u16 f2bf(float f) {
  unsigned int v; __builtin_memcpy(&v, &f, 4);
  v = v + 0x7FFFu + ((v >> 16) & 1u);   // RNE
  return (u16)(v >> 16);
}

// async global->LDS, 16B per lane; LDS dest = wave-uniform base + lane*16
__device__ __forceinline__ void gll16(const void* g, void* l) {
  __builtin_amdgcn_global_load_lds(
      (__attribute__((address_space(1))) void*)(g),
      (__attribute__((address_space(3))) void*)(l), 16, 0, 0);
}

// ---------------------------------------------------------------------------
// fp32 -> bf16 bulk convert (n multiple of 2048); 8 elems/thread
// ---------------------------------------------------------------------------
__global__ __launch_bounds__(256) void f32_to_bf16(const float* __restrict__ in,
                                                   u16* __restrict__ out, size_t n) {
  size_t i = ((size_t)blockIdx.x * 256 + threadIdx.x) * 8;
  if (i >= n) return;
  float4 a = *(const float4*)(in + i);
  float4 b = *(const float4*)(in + i + 4);
  union { u16 o[8]; uint4 v; } u;
  u.o[0] = f2bf(a.x); u.o[1] = f2bf(a.y); u.o[2] = f2bf(a.z); u.o[3] = f2bf(a.w);
  u.o[4] = f2bf(b.x); u.o[5] = f2bf(b.y); u.o[6] = f2bf(b.z); u.o[7] = f2bf(b.w);
  *(uint4*)(out + i) = u.v;
}

// ---------------------------------------------------------------------------
// Tiled transpose + fp32->bf16: out[n][k] = bf16(in[k][n]), K,N multiples of 64
// ---------------------------------------------------------------------------
__global__ __launch_bounds__(256) void ktranspose_f(const float* __restrict__ in,
                                                    u16* __restrict__ out, int K, int N) {
  __shared__ __align__(16) u16 tile[64 * 65];
  int n0 = blockIdx.x * 64, k0 = blockIdx.y * 64;
  int tx = threadIdx.x & 63, ty = threadIdx.x >> 6;
  for (int r = 0; r < 16; ++r) {
    int kk = r * 4 + ty;
    tile[kk * 65 + tx] = f2bf(in[(size_t)(k0 + kk) * N + n0 + tx]);
  }
  __syncthreads();
  for (int r = 0; r < 16; ++r) {
    int nn = r * 4 + ty;
    out[(size_t)(n0 + nn) * K + k0 + tx] = tile[tx * 65 + nn];
  }
}

// ---------------------------------------------------------------------------
// 256x256 ring-buffered GEMM: C[M,N] = A[M,K] @ Bt[N,K]^T.
// BK=32, 4-buffer LDS ring (128 KiB), 8 waves (2Mx4N), per-wave 128x64
// output, mfma 16x16x32 bf16, 1 block/CU. ONE barrier per tile (round 7).
//
// Round-7 post-mortem: structure good (137us, MfmaUtil 45%) but the 64B-row
// swizzle slot^=(r&3) left SQ_LDS_BANK_CONFLICT at 1.26e7. Root cause: the
// LDS pipe services b128 wave reads in 8-LANE GROUPS (128B/cy); conflict-
// freedom needs slot8 = addr/16 mod 8 to be a PERMUTATION within every 8
// consecutive lanes. r&3 has period 4 -> {q,4+q^1,q^2,4+q^3} twice per
// group = 2-way alias on every read (round 6's l15&7 swizzle gave 0).
//
// Fix (this round's ONLY change): swizzle on bit 1-2 of the row:
//   slot_lds = slot_global ^ ((row>>1)&3)
// slot8(lane) = (l15&1)*4 + (quad ^ ((l15>>1)&3)) -> enumerates 0..7 within
// every 8-lane group (checked for all quads). Involution (rule 21):
//   stage: row = w*32 + (lane>>2) (+16, same (r>>1)&3) -> source slot =
//          (lane&3) ^ ((lane>>3)&3)
//   read:  all row-base terms are multiples of 8 rows -> (r>>1)&3 = (l15>>1)&3
// ---------------------------------------------------------------------------
template <typename OutT>
__global__ __launch_bounds__(512, 2) void gemm_bt4(const u16* __restrict__ A,
                                                   const u16* __restrict__ Bt,
                                                   OutT* __restrict__ C,
                                                   int M, int N, int K) {
  __shared__ __align__(16) u16 AS[4][256 * 32];   // 16KB per buffer
  __shared__ __align__(16) u16 BS[4][256 * 32];
  (void)M;
  int tid = threadIdx.x;
  int w = tid >> 6, lane = tid & 63, quad = lane >> 4, l15 = lane & 15;
  int wr = w >> 2, wc = w & 3;          // 2 M-warps x 4 N-warps

  // XCD-bijective block swizzle (grid counts are multiples of 8 here)
  int nwg = gridDim.x * gridDim.y;
  int id = blockIdx.y * gridDim.x + blockIdx.x;
  int swz = (id & 7) * (nwg >> 3) + (id >> 3);
  int bx = swz % gridDim.x, by = swz / gridDim.x;
  int m0 = by * 256, n0 = bx * 256;

  size_t Kb = (size_t)K * 2;            // bytes per row
  int nt = K >> 5;                      // K-tiles of 32

  // staging decode: wave w stages rows [w*32, w*32+32) of A and Bt.
  // LDS slot idx = w*128 + lane (+64 for 2nd load) -> row = w*32+(lane>>2)
  // (+16), slot-in-row = lane&3. Pre-swizzled source slot (see header):
  int srow = w * 32 + (lane >> 2);
  int gslot = ((lane & 3) ^ ((lane >> 3) & 3)) * 16;
  auto stage = [&](int tk) {
    int bsel = tk & 3;
    char* Ad = (char*)AS[bsel] + (w * 2) * 1024 + lane * 16;
    char* Bd = (char*)BS[bsel] + (w * 2) * 1024 + lane * 16;
    const char* As0 = (const char*)A + (size_t)(m0 + srow) * Kb + (size_t)tk * 64 + gslot;
    const char* Bs0 = (const char*)Bt + (size_t)(n0 + srow) * Kb + (size_t)tk * 64 + gslot;
    gll16(As0, Ad);
    gll16(As0 + 16 * Kb, Ad + 1024);
    gll16(Bs0, Bd);
    gll16(Bs0 + 16 * Kb, Bd + 1024);
  };

  f32x4 acc[2][4][2][2];                // [mh][f][nh][g]
#pragma unroll
  for (int mh = 0; mh < 2; ++mh)
#pragma unroll
    for (int f = 0; f < 4; ++f)
#pragma unroll
      for (int nh = 0; nh < 2; ++nh)
#pragma unroll
        for (int g = 0; g < 2; ++g) acc[mh][f][nh][g] = (f32x4){0.f, 0.f, 0.f, 0.f};

  // prologue: stage tiles 0,1,2 (12 loads out); tile 0 landed; barrier.
  stage(0); stage(1); stage(2);
  asm volatile("s_waitcnt vmcnt(8)" ::: "memory");
  __builtin_amdgcn_s_barrier();

  int rdoff = ((quad ^ ((l15 >> 1) & 3)) << 4);   // swizzled slot byte
  int aRowB = (wr * 64 + l15) * 64 + rdoff;       // + (mh*128 + f*16)*64
  int bRowB = (wc * 32 + l15) * 64 + rdoff;       // + (nh*128 + g*16)*64

  for (int t = 0; t < nt; ++t) {
    const char* Ab = (const char*)AS[t & 3];
    const char* Bb = (const char*)BS[t & 3];

    bfrag aA[2][4], bB[2][2];
#pragma unroll
    for (int mh = 0; mh < 2; ++mh)
#pragma unroll
      for (int f = 0; f < 4; ++f)
        aA[mh][f] = *(const bfrag*)(Ab + aRowB + (mh * 128 + f * 16) * 64);
#pragma unroll
    for (int nh = 0; nh < 2; ++nh)
#pragma unroll
      for (int g = 0; g < 2; ++g)
        bB[nh][g] = *(const bfrag*)(Bb + bRowB + (nh * 128 + g * 16) * 64);

    if (t + 3 < nt) stage(t + 3);       // into buf[(t+3)&3] (safe: see header)

    __builtin_amdgcn_s_setprio(1);
#pragma unroll
    for (int mh = 0; mh < 2; ++mh)
#pragma unroll
      for (int f = 0; f < 4; ++f)
#pragma unroll
        for (int nh = 0; nh < 2; ++nh)
#pragma unroll
          for (int g = 0; g < 2; ++g)
            acc[mh][f][nh][g] = __builtin_amdgcn_mfma_f32_16x16x32_bf16(
                aA[mh][f], bB[nh][g], acc[mh][f][nh][g], 0, 0, 0);
    __builtin_amdgcn_s_setprio(0);

    asm volatile("s_waitcnt lgkmcnt(0)" ::: "memory");  // own reads drained
    __builtin_amdgcn_sched_barrier(0);                  // rule-18 insurance
    if (t + 3 < nt)
      asm volatile("s_waitcnt vmcnt(8)" ::: "memory");  // t+1 landed (counted)
    else if (t + 1 < nt)
      asm volatile("s_waitcnt vmcnt(0)" ::: "memory");  // epilogue drain
    __builtin_amdgcn_s_barrier();                       // ONE barrier per tile
  }

  // epilogue: C/D layout col=lane&15, row=quad*4+reg (m89/m91 verified)
#pragma unroll
  for (int mh = 0; mh < 2; ++mh)
#pragma unroll
    for (int f = 0; f < 4; ++f)
#pragma unroll
      for (int nh = 0; nh < 2; ++nh)
#pragma unroll
        for (int g = 0; g < 2; ++g)
#pragma unroll
          for (int rr = 0; rr < 4; ++rr) {
            int row = m0 + wr * 64 + mh * 128 + f * 16 + quad * 4 + rr;
            int col = n0 + wc * 32 + nh * 128 + g * 16 + l15;
            float v = acc[mh][f][nh][g][rr];
            if constexpr (__is_same(OutT, float))
              C[(size_t)row * N + col] = v;
            else
              C[(size_t)row * N + col] = f2bf(v);
          }
}

// ---------------------------------------------------------------------------
// RoPE (interleaved pairs) + scatter into Q[b][h][s][d] (token order) and
// paged K/V caches [blk][kvh][off][d] honoring block_tables.
// ---------------------------------------------------------------------------
__global__ __launch_bounds__(256) void rope_scatter(const u16* __restrict__ xqkv,
                                                    const int* __restrict__ positions,
                                                    const int* __restrict__ btab,
                                                    u16* __restrict__ qb,
                                                    u16* __restrict__ kb,
                                                    u16* __restrict__ vbuf) {
  int t = blockIdx.x;
  int tid = threadIdx.x;
  int b = t >> 10, srow = t & 1023;
  int pos = positions[t];
  int blk = btab[b * (SEQ / BLKSZ) + (pos >> 4)];
  int off = pos & (BLKSZ - 1);
  int c0 = tid * 16;

  struct __align__(16) { uint4 a, bq; } vv, oo;
  const u16* src = xqkv + (size_t)t * 4096 + c0;
  vv.a  = *(const uint4*)src;
  vv.bq = *(const uint4*)(src + 8);
  const u16* v = (const u16*)&vv;
  u16* o = (u16*)&oo;

  if (c0 < 3072) {  // Q or K section: apply RoPE on (even,odd) pairs
    int dbase = c0 & 127;
    float fpos = (float)pos;
    for (int j = 0; j < 8; ++j) {
      int i = (dbase >> 1) + j;                       // freq index 0..63
      float inv = exp2f(-(float)i * (13.287712379549449f / 64.0f)); // 10000^(-i/64)
      float ang = fpos * inv;
      float sn, cs;
      sincosf(ang, &sn, &cs);
      float fr = bf2f(v[2 * j]), fi = bf2f(v[2 * j + 1]);
      o[2 * j]     = f2bf(fr * cs - fi * sn);
      o[2 * j + 1] = f2bf(fr * sn + fi * cs);
    }
  } else {
    for (int j = 0; j < 16; ++j) o[j] = v[j];
  }

  u16* dst;
  if (c0 < 2048) {
    int head = c0 >> 7, d0 = c0 & 127;
    dst = qb + (((size_t)(b * NH + head)) * SEQ + srow) * HD + d0;
  } else if (c0 < 3072) {
    int cc = c0 - 2048;
    int kvh = cc >> 7, d0 = cc & 127;
    dst = kb + (((size_t)(blk * NKV + kvh) * BLKSZ + off)) * HD + d0;
  } else {
    int cc = c0 - 3072;
    int kvh = cc >> 7, d0 = cc & 127;
    dst = vbuf + (((size_t)(blk * NKV + kvh) * BLKSZ + off)) * HD + d0;
  }
  *(uint4*)dst = oo.a;
  *(uint4*)(dst + 8) = oo.bq;
}

// ---------------------------------------------------------------------------
// Flash attention v2, paged cache — KVT=64 + T14 (verified rounds 4/6/7;
// unchanged).
// ---------------------------------------------------------------------------
#define KVT 64
#define KS_STRIDE 272   // bytes per K token row (128*2 + 16 pad)
#define VT_STRIDE 144   // bytes per V d row (64*2 + 16 pad)
#define PS_STRIDE 144   // bytes per P q row (64*2 + 16 pad)

__global__ __launch_bounds__(512) void attn_kernel(const u16* __restrict__ Q,
                                                   const u16* __restrict__ Kc,
                                                   const u16* __restrict__ Vc,
                                                   const int* __restrict__ positions,
                                                   const int* __restrict__ btab,
                                                   u16* __restrict__ O) {
  __shared__ __align__(16) u16 Ks[KVT * (KS_STRIDE / 2)];
  __shared__ __align__(16) u16 Vt[HD * (VT_STRIDE / 2)];
  __shared__ __align__(16) u16 Ps[8 * 16 * (PS_STRIDE / 2)];
  const float SM_SCALE = 0.08838834764831845f; // 1/sqrt(128)
  const float LOG2E    = 1.4426950408889634f;
  const float C1       = SM_SCALE * LOG2E;
  const float NEGBIG   = -30000.0f;
  const float NEGINIT  = -1e30f;
  const float DEFER2   = 8.0f * LOG2E;

  int tid = threadIdx.x;
  int wave = tid >> 6, lane = tid & 63, quad = lane >> 4, l15 = lane & 15;
  int bid = blockIdx.x;
  int bh = bid >> 2, pr = bid & 3;
  int b = bh >> 4, h = bh & 15, kvh = h >> 1;
  const int* btrow = btab + b * (SEQ / BLKSZ);

  char* KsB = (char*)Ks;
  char* VtB = (char*)Vt;
  char* myPsB = (char*)Ps + wave * 16 * PS_STRIDE;

  int tokA = tid >> 4;
  int tokB = tokA + 32;
  int dgK  = tid & 15;
  int tokV = (tid & 31) * 2;
  int vd0  = (tid >> 5) * 8;

  uint4 kr0, kr1, vr0, vr1;

  auto load_tile = [&](int kti) {
    int i0 = kti >> 4;
    int b0 = btrow[i0], b1 = btrow[i0 + 1], b2 = btrow[i0 + 2], b3 = btrow[i0 + 3];
    const u16* KA = Kc + ((size_t)(((tokA < 16) ? b0 : b1) * NKV + kvh) * BLKSZ + (tokA & 15)) * HD + dgK * 8;
    const u16* KB = Kc + ((size_t)(((tokB < 48) ? b2 : b3) * NKV + kvh) * BLKSZ + (tokB & 15)) * HD + dgK * 8;
    kr0 = *(const uint4*)KA;
    kr1 = *(const uint4*)KB;
    int bv = (tokV < 16) ? b0 : (tokV < 32) ? b1 : (tokV < 48) ? b2 : b3;
    const u16* VA = Vc + ((size_t)(bv * NKV + kvh) * BLKSZ + (tokV & 15)) * HD + vd0;
    vr0 = *(const uint4*)VA;
    vr1 = *(const uint4*)(VA + HD);
  };

  for (int pass = 0; pass < 2; ++pass) {
    int yt = pass ? (7 - pr) : pr;
    int q0 = yt * 128;
    int qw = q0 + wave * 16;

    const u16* Qbase = Q + ((size_t)bh * SEQ + qw) * HD;

    bfrag aq[4];
#pragma unroll
    for (int kb2 = 0; kb2 < 4; ++kb2)
      aq[kb2] = *(const bfrag*)(Qbase + (size_t)l15 * HD + kb2 * 32 + quad * 8);

    int qpos[4];
#pragma unroll
    for (int r = 0; r < 4; ++r)
      qpos[r] = positions[(size_t)b * SEQ + qw + quad * 4 + r];

    f32x4 oa[8];
#pragma unroll
    for (int jd = 0; jd < 8; ++jd) oa[jd] = (f32x4){0.f, 0.f, 0.f, 0.f};
    float m2_i[4], l_i[4];
#pragma unroll
    for (int r = 0; r < 4; ++r) { m2_i[r] = NEGINIT; l_i[r] = 0.f; }

    int kend = q0 + 128;
    load_tile(0);

    for (int kt = 0; kt < kend; kt += KVT) {
      __syncthreads();
      *(uint4*)(KsB + tokA * KS_STRIDE + dgK * 16) = kr0;
      *(uint4*)(KsB + tokB * KS_STRIDE + dgK * 16) = kr1;
      {
        const u16* p0 = (const u16*)&vr0;
        const u16* p1 = (const u16*)&vr1;
#pragma unroll
        for (int jj = 0; jj < 8; ++jj) {
          unsigned int val = (unsigned int)p0[jj] | ((unsigned int)p1[jj] << 16);
          *(unsigned int*)(VtB + (vd0 + jj) * VT_STRIDE + tokV * 2) = val;
        }
      }
      __syncthreads();

      if (kt + KVT < kend) load_tile(kt + KVT);

      if (kt <= qw + 15) {
        f32x4 sa[4];
#pragma unroll
        for (int jn = 0; jn < 4; ++jn) sa[jn] = (f32x4){0.f, 0.f, 0.f, 0.f};
#pragma unroll
        for (int kb2 = 0; kb2 < 4; ++kb2) {
#pragma unroll
          for (int jn = 0; jn < 4; ++jn) {
            bfrag bk = *(const bfrag*)(KsB + (jn * 16 + l15) * KS_STRIDE + (kb2 * 4 + quad) * 16);
            sa[jn] = __builtin_amdgcn_mfma_f32_16x16x32_bf16(aq[kb2], bk, sa[jn], 0, 0, 0);
          }
        }

        float m2x[4];
#pragma unroll
        for (int r = 0; r < 4; ++r) {
#pragma unroll
          for (int jn = 0; jn < 4; ++jn) {
            float s = sa[jn][r];
            if (kt + jn * 16 + l15 > qpos[r]) s = NEGBIG;
            sa[jn][r] = s;
          }
          float m0 = fmaxf(fmaxf(sa[0][r], sa[1][r]), fmaxf(sa[2][r], sa[3][r]));
          m0 = fmaxf(m0, __shfl_xor(m0, 1, 64));
          m0 = fmaxf(m0, __shfl_xor(m0, 2, 64));
          m0 = fmaxf(m0, __shfl_xor(m0, 4, 64));
          m0 = fmaxf(m0, __shfl_xor(m0, 8, 64));
          m2x[r] = m0 * C1;
        }

        bool ok = (m2x[0] <= m2_i[0] + DEFER2) && (m2x[1] <= m2_i[1] + DEFER2) &&
                  (m2x[2] <= m2_i[2] + DEFER2) && (m2x[3] <= m2_i[3] + DEFER2);
        if (__all(ok)) {
#pragma unroll
          for (int r = 0; r < 4; ++r) {
            float rs = 0.f;
#pragma unroll
            for (int jn = 0; jn < 4; ++jn) {
              float pv = exp2f(sa[jn][r] * C1 - m2_i[r]);
              sa[jn][r] = pv;
              rs += pv;
            }
            rs += __shfl_xor(rs, 1, 64);
            rs += __shfl_xor(rs, 2, 64);
            rs += __shfl_xor(rs, 4, 64);
            rs += __shfl_xor(rs, 8, 64);
            l_i[r] += rs;
          }
        } else {
          float alpha[4];
#pragma unroll
          for (int r = 0; r < 4; ++r) {
            float m2n = fmaxf(m2_i[r], m2x[r]);
            float al = exp2f(m2_i[r] - m2n);
            float rs = 0.f;
#pragma unroll
            for (int jn = 0; jn < 4; ++jn) {
              float pv = exp2f(sa[jn][r] * C1 - m2n);
              sa[jn][r] = pv;
              rs += pv;
            }
            rs += __shfl_xor(rs, 1, 64);
            rs += __shfl_xor(rs, 2, 64);
            rs += __shfl_xor(rs, 4, 64);
            rs += __shfl_xor(rs, 8, 64);
            l_i[r] = l_i[r] * al + rs;
            m2_i[r] = m2n;
            alpha[r] = al;
          }
#pragma unroll
          for (int jd = 0; jd < 8; ++jd) {
            oa[jd][0] *= alpha[0];
            oa[jd][1] *= alpha[1];
            oa[jd][2] *= alpha[2];
            oa[jd][3] *= alpha[3];
          }
        }

#pragma unroll
        for (int r = 0; r < 4; ++r) {
          int q = quad * 4 + r;
#pragma unroll
          for (int jn = 0; jn < 4; ++jn)
            *(u16*)(myPsB + q * PS_STRIDE + (jn * 16 + l15) * 2) = f2bf(sa[jn][r]);
        }
        bfrag ap0 = *(const bfrag*)(myPsB + l15 * PS_STRIDE + quad * 16);
        bfrag ap1 = *(const bfrag*)(myPsB + l15 * PS_STRIDE + 64 + quad * 16);
#pragma unroll
        for (int jd = 0; jd < 8; ++jd) {
          int d = jd * 16 + l15;
          bfrag bv0 = *(const bfrag*)(VtB + d * VT_STRIDE + quad * 16);
          bfrag bv1 = *(const bfrag*)(VtB + d * VT_STRIDE + 64 + quad * 16);
          oa[jd] = __builtin_amdgcn_mfma_f32_16x16x32_bf16(ap0, bv0, oa[jd], 0, 0, 0);
          oa[jd] = __builtin_amdgcn_mfma_f32_16x16x32_bf16(ap1, bv1, oa[jd], 0, 0, 0);
        }
      }
    }

#pragma unroll
    for (int r = 0; r < 4; ++r) {
      float inv = 1.0f / fmaxf(l_i[r], 1e-30f);
      size_t trow = (size_t)b * SEQ + qw + quad * 4 + r;
#pragma unroll
      for (int jd = 0; jd < 8; ++jd)
        O[trow * 2048 + (size_t)h * HD + jd * 16 + l15] = f2bf(oa[jd][r] * inv);
    }
  }
}

// ---------------------------------------------------------------------------
extern "C" void kernel_launch(void* const* d_in, const int* in_sizes, int n_in,
                              void* d_out, int out_size, void* d_ws, size_t ws_size,
                              hipStream_t stream) {
  (void)in_sizes; (void)n_in; (void)out_size;
  const float* xf  = (const float*)d_in[0];
  const float* wqf = (const float*)d_in[1];
  const float* wkf = (const float*)d_in[2];
  const float* wvf = (const float*)d_in[3];
  const float* wof = (const float*)d_in[4];
  const int* positions = (const int*)d_in[7];
  const int* btab      = (const int*)d_in[10];
  float* out = (float*)d_out;

  u16* ws    = (u16*)d_ws;
  u16* woT   = ws;                                  // [2048][2048]
  u16* wqkvT = woT + (size_t)2048 * 2048;           // [4096][2048]
  u16* xbf   = wqkvT + (size_t)4096 * 2048;         // [8192][2048]
  u16* xqkv  = xbf + (size_t)8192 * 2048;           // [8192][4096]
  u16* qb    = xqkv + (size_t)8192 * 4096;          // [8][16][1024][128]
  u16* kbuf  = qb + (size_t)8192 * 2048;            // paged K
  u16* vbuf  = kbuf + (size_t)8192 * 1024;          // paged V
  u16* wsend = vbuf + (size_t)8192 * 1024;

  size_t base_elems = (size_t)(wsend - ws);
  size_t obuf_elems = (size_t)8192 * 2048;
  u16* obuf;
  if (ws_size >= (base_elems + obuf_elems) * sizeof(u16))
    obuf = wsend;
  else
    obuf = wqkvT;

  if (ws_size < base_elems * sizeof(u16)) return;

  f32_to_bf16<<<dim3(8192), 256, 0, stream>>>(xf, xbf, (size_t)8192 * 2048);
  ktranspose_f<<<dim3(32, 32), 256, 0, stream>>>(wqf, wqkvT, 2048, 2048);
  ktranspose_f<<<dim3(16, 32), 256, 0, stream>>>(wkf, wqkvT + (size_t)2048 * 2048, 2048, 1024);
  ktranspose_f<<<dim3(16, 32), 256, 0, stream>>>(wvf, wqkvT + (size_t)3072 * 2048, 2048, 1024);
  ktranspose_f<<<dim3(32, 32), 256, 0, stream>>>(wof, woT, 2048, 2048);
  // QKV projection: 256x256 ring-buffered GEMM (512 blocks, %8==0)
  gemm_bt4<u16><<<dim3(16, 32), 512, 0, stream>>>(xbf, wqkvT, xqkv, 8192, 4096, 2048);
  rope_scatter<<<dim3(8192), 256, 0, stream>>>(xqkv, positions, btab, qb, kbuf, vbuf);
  attn_kernel<<<dim3(512), 512, 0, stream>>>(qb, kbuf, vbuf, positions, btab, obuf);
  // output projection (256 blocks, %8==0)
  gemm_bt4<float><<<dim3(8, 32), 512, 0, stream>>>(obuf, woT, out, 8192, 2048, 2048);
}